// Round 5
// baseline (20480.190 us; speedup 1.0000x reference)
//
#include <hip/hip_runtime.h>

typedef _Float16 f16;
typedef f16  f16x8 __attribute__((ext_vector_type(8)));
typedef __fp16 h16x2 __attribute__((ext_vector_type(2)));
typedef float f32x4 __attribute__((ext_vector_type(4)));
typedef float f32x16 __attribute__((ext_vector_type(16)));
typedef unsigned long long u64;

// problem dims: B=128, T=256, E=H=512, L=4, 4H=2048
// ws layout (bytes)
#define OFF_XF  0ull          // fwd activation stream (T,128,512) f32 : 64 MB
#define OFF_XR  67108864ull   // time-reversed stream                  : 64 MB
#define OFF_WP  134217728ull  // packed lstm weights f16, frag-ordered [L][32cb][128KB]: 16 MB
#define OFF_WO  150994944ull  // out_W  f16 [512][1024]
#define OFF_WH  152043520ull  // hid_W  f16
#define OFF_WC  153092096ull  // cell_W f16
#define OFF_BC  154140672ull  // combined bias f32 [L][2048] (packed order)
#define OFF_HB  154173440ull  // h exchange buf f16 [dir][parity][128][512]
#define OFF_HT  154697728ull  // hT f32 [L][dir][128][512]
#define OFF_CT  156794880ull  // cT f32
#define OFF_CNT 158892032ull  // counters int [L][dir][half][256]

__device__ __forceinline__ float sigm(float x) { return 1.0f / (1.0f + __expf(-x)); }
__device__ __forceinline__ float ftanh(float x) { return 1.0f - 2.0f / (__expf(2.0f * x) + 1.0f); }

__device__ __forceinline__ f16x8 cvt8(const float* p) {
    float4 a0 = *(const float4*)p;
    float4 a1 = *(const float4*)(p + 4);
    union { f16x8 v; h16x2 h[4]; } u;
    u.h[0] = __builtin_amdgcn_cvt_pkrtz(a0.x, a0.y);
    u.h[1] = __builtin_amdgcn_cvt_pkrtz(a0.z, a0.w);
    u.h[2] = __builtin_amdgcn_cvt_pkrtz(a1.x, a1.y);
    u.h[3] = __builtin_amdgcn_cvt_pkrtz(a1.z, a1.w);
    return u.v;
}

// ---------------- prep: LSTM weights -> fragment-ordered f16 tiles ------------------------
// Tile (l,cb): 64 packed cols (q = gate*16 + jl) x 1024 K, stored as
//   [ct(2)][frag(64)][lane(64)][8 f16]  so ds_read_b128 per lane is stride-1.
// frag f: k = (f>>5)*512 + (f&31)*16 + (lane>>5)*8 ; col q = ct*32 + (lane&31)
__global__ __launch_bounds__(256) void prep_w(
    const float* __restrict__ Wih, const float* __restrict__ Whh, f16* __restrict__ Wp)
{
    const int l = blockIdx.x >> 5, cb = blockIdx.x & 31;
    f16* dst = Wp + (size_t)blockIdx.x * 65536;
    for (int g = threadIdx.x; g < 8192; g += 256) {      // 8-elem groups
        const int ct = g >> 12;
        const int r  = g & 4095;
        const int f  = r >> 6;
        const int ln = r & 63;
        const int q  = ct*32 + (ln & 31);
        const int orig = (q >> 4)*512 + cb*16 + (q & 15);
        const int k0 = ((f >> 5) << 9) + (f & 31)*16 + ((ln >> 5) << 3);
        const float* src = (k0 < 512)
            ? Wih + (((size_t)(l*2048 + orig)) << 9) + k0
            : Whh + (((size_t)(l*2048 + orig)) << 9) + (k0 - 512);
        *(f16x8*)(dst + (size_t)g * 8) = cvt8(src);
    }
}

// ---------------- prep: proj weights f16, combined bias, counters -------------------------
__global__ __launch_bounds__(256) void prep_misc(
    const float* __restrict__ bih, const float* __restrict__ bhh,
    const float* __restrict__ oW, const float* __restrict__ hW, const float* __restrict__ cW,
    f16* __restrict__ Wo, f16* __restrict__ Wh, f16* __restrict__ Wc,
    float* __restrict__ bc, int* __restrict__ cnt)
{
    const int blk = blockIdx.x, tid = threadIdx.x;
    if (blk < 1536) {
        const int which = blk >> 9;
        const int n = blk & 511;
        const float* s = which == 0 ? oW : (which == 1 ? hW : cW);
        f16* d = which == 0 ? Wo : (which == 1 ? Wh : Wc);
        for (int k = tid; k < 1024; k += 256)
            d[((size_t)n << 10) + k] = (f16)s[((size_t)n << 10) + k];
    } else if (blk == 1536) {
        for (int i = tid; i < 8192; i += 256) {
            const int l = i >> 11, p = i & 2047;
            const int cb = p >> 6, gate = (p >> 4) & 3, j = p & 15;
            const int orig = l*2048 + gate*512 + cb*16 + j;
            bc[i] = bih[orig] + bhh[orig];
        }
    } else {
        for (int i = tid; i < 4096; i += 256) cnt[i] = 0;
    }
}

// ---------------- embedding + relu, fwd and time-reversed streams -------------------------
__global__ __launch_bounds__(256) void embed_relu(
    const int* __restrict__ ids, const float* __restrict__ emb,
    float* __restrict__ Xf, float* __restrict__ Xr)
{
    const int blk = blockIdx.x;               // 0..32767
    const int b = blk >> 8, t = blk & 255;
    const int id = ids[b*256 + t];
    float2 v = *((const float2*)(emb + ((size_t)id << 9)) + threadIdx.x);
    v.x = fmaxf(v.x, 0.f); v.y = fmaxf(v.y, 0.f);
    const size_t e2 = (size_t)threadIdx.x * 2;
    *(float2*)(Xf + (((size_t)t*128 + b) << 9) + e2) = v;
    *(float2*)(Xr + (((size_t)(255 - t)*128 + b) << 9) + e2) = v;
}

// ---------------- persistent per-layer LSTM, relaxed IC-atomic sync -----------------------
// grid 128; launched block b -> (dir,half) group g2=(b>>1)&3 on XCDs {2g2,2g2+1} (b%8 rr).
// Block: 64 rows (one half) x 64 gate cols; W tile in LDS (128KB frag-ordered);
// waves = 2rt x 2ct quadrants of 32x32x16 MFMA; gates bounce via padded LDS Gs[64][68].
__global__ __launch_bounds__(256, 1) void lstm_layer(
    const int l,
    const f16* __restrict__ Wp, const float* __restrict__ bc,
    float* __restrict__ Xf, float* __restrict__ Xr,
    f16* __restrict__ hbuf, float* __restrict__ hT, float* __restrict__ cT,
    int* __restrict__ cnt)
{
    extern __shared__ char smem[];
    f16*   Wlds = (f16*)smem;                 // 2ct x 64frag x 64lane x 8 f16 = 128KB
    float* Gs   = (float*)(smem + 131072);    // 64 x 68 f32 (padded)

    const int tid = threadIdx.x;
    const int b   = blockIdx.x;
    const int g2  = (b >> 1) & 3;             // (dir,half) group
    const int cb  = ((b >> 3) << 1) | (b & 1);
    const int dir = g2 >> 1;
    const int half= g2 & 1;

    const int w   = tid >> 6;                 // wave id
    const int rt  = w >> 1, ct = w & 1;       // row-tile / col-tile quadrant
    const int ln  = tid & 63;
    const int l31 = ln & 31;
    const int hi  = ln >> 5;

    {   // stage pre-packed W tile (linear copy)
        const float4* src = (const float4*)(Wp + (size_t)(l*32 + cb) * 65536);
        float4* dst = (float4*)Wlds;
        for (int i = tid; i < 8192; i += 256) dst[i] = src[i];
    }

    float* X = dir ? Xr : Xf;
    f16* hb = hbuf + (size_t)dir * 131072;
    int* cp = cnt + (((l*2 + dir)*2 + half) << 8);

    const int arow = half*64 + rt*32 + l31;   // A row (batch index)
    const int kb0  = hi << 3;
    const f16* wbase = Wlds + (ct << 15);     // ct*32768 elements

    // elementwise mapping: thread -> col jl, rows rb..rb+3 (of this half)
    const int jl   = tid & 15;
    const int rb   = (tid >> 4) << 2;
    const int erow = half*64 + rb;
    const int ecol = cb*16 + jl;
    const float bi_ = bc[l*2048 + cb*64 +      jl];
    const float bf_ = bc[l*2048 + cb*64 + 16 + jl];
    const float bg_ = bc[l*2048 + cb*64 + 32 + jl];
    const float bo_ = bc[l*2048 + cb*64 + 48 + jl];

    float creg[4] = {0.f, 0.f, 0.f, 0.f};
    float xdef[4] = {0.f, 0.f, 0.f, 0.f};

    __syncthreads();                          // W staged

    for (int t = 0; t < 256; ++t) {
        if (t > 0) {
            // relaxed poll (no cache maintenance!) — all threads
            int gd = 0;
            while (__hip_atomic_load(cp + (t - 1), __ATOMIC_RELAXED, __HIP_MEMORY_SCOPE_AGENT) < 32) {
                __builtin_amdgcn_s_sleep(2);
                if (++gd > (1 << 16)) break;  // deadlock bail
            }
            __builtin_amdgcn_sched_barrier(0);
            // deferred residual write of X[t-1] (all group reads of it are done)
            float* xw = X + (((size_t)(t - 1)) << 16) + (((size_t)erow) << 9) + ecol;
            xw[0] = xdef[0]; xw[512] = xdef[1]; xw[1024] = xdef[2]; xw[1536] = xdef[3];
        }

        f32x16 acc = {};
        // issue h loads early (IC, relaxed) so X-half compute hides their latency
        f16x8 uu[32];
        if (t > 0) {
            const f16* hrow = hb + (((size_t)((t - 1) & 1)) << 16) + (((size_t)arow) << 9);
            #pragma unroll
            for (int ks = 0; ks < 32; ++ks) {
                const u64* hp = (const u64*)(hrow + ks*16 + kb0);
                union { u64 q[2]; f16x8 v; } uv;
                uv.q[0] = __hip_atomic_load(hp,     __ATOMIC_RELAXED, __HIP_MEMORY_SCOPE_AGENT);
                uv.q[1] = __hip_atomic_load(hp + 1, __ATOMIC_RELAXED, __HIP_MEMORY_SCOPE_AGENT);
                uu[ks] = uv.v;
            }
        }
        // X half of K (frag f = ks)
        const float* xrow = X + (((size_t)t) << 16) + (((size_t)arow) << 9);
        #pragma unroll
        for (int ks = 0; ks < 32; ++ks) {
            f16x8 af = cvt8(xrow + ks*16 + kb0);
            f16x8 bf = *(const f16x8*)(wbase + ((ks) << 9) + (ln << 3));
            acc = __builtin_amdgcn_mfma_f32_32x32x16_f16(af, bf, acc, 0, 0, 0);
        }
        // h half of K (frag f = 32+ks)
        if (t > 0) {
            #pragma unroll
            for (int ks = 0; ks < 32; ++ks) {
                f16x8 bf = *(const f16x8*)(wbase + ((32 + ks) << 9) + (ln << 3));
                acc = __builtin_amdgcn_mfma_f32_32x32x16_f16(uu[ks], bf, acc, 0, 0, 0);
            }
        }
        // gates -> padded LDS (write: lanes span 32 cols -> conflict-free)
        {
            const int grow0 = rt*32 + 4*hi;
            const int q = ct*32 + l31;
            #pragma unroll
            for (int r = 0; r < 16; ++r)
                Gs[(grow0 + (r & 3) + 8*(r >> 2))*68 + q] = acc[r];
        }
        __syncthreads();
        // elementwise (per-thread fp32 cell state), publish h to IC
        {
            const float* xo = X + (((size_t)t) << 16) + (((size_t)erow) << 9) + ecol;
            #pragma unroll
            for (int rr = 0; rr < 4; ++rr) {
                const float gi = Gs[(rb + rr)*68 +      jl] + bi_;
                const float gf = Gs[(rb + rr)*68 + 16 + jl] + bf_;
                const float gg = Gs[(rb + rr)*68 + 32 + jl] + bg_;
                const float go = Gs[(rb + rr)*68 + 48 + jl] + bo_;
                const float cn = sigm(gf)*creg[rr] + sigm(gi)*ftanh(gg);
                const float hv = sigm(go)*ftanh(cn);
                creg[rr] = cn;
                xdef[rr] = xo[(size_t)rr << 9] + hv;
                union { f16 h; unsigned short u; } cu; cu.h = (f16)hv;
                __hip_atomic_store(
                    (unsigned short*)(hb + (((size_t)(t & 1)) << 16) + (((size_t)(erow + rr)) << 9) + ecol),
                    cu.u, __ATOMIC_RELAXED, __HIP_MEMORY_SCOPE_AGENT);
                if (t == 255) {
                    const size_t o = (((size_t)(l*2 + dir)*128 + erow + rr) << 9) + ecol;
                    hT[o] = hv; cT[o] = cn;
                }
            }
        }
        __syncthreads();   // drains vmcnt: all h stores of this block at IC
        if (tid == 0)
            __hip_atomic_fetch_add(cp + t, 1, __ATOMIC_RELAXED, __HIP_MEMORY_SCOPE_AGENT);
    }

    // flush final deferred residual write (after everyone has read X[255])
    {
        int gd = 0;
        while (__hip_atomic_load(cp + 255, __ATOMIC_RELAXED, __HIP_MEMORY_SCOPE_AGENT) < 32) {
            __builtin_amdgcn_s_sleep(2);
            if (++gd > (1 << 16)) break;
        }
        float* xw = X + (((size_t)255) << 16) + (((size_t)erow) << 9) + ecol;
        xw[0] = xdef[0]; xw[512] = xdef[1]; xw[1024] = xdef[2]; xw[1536] = xdef[3];
    }
}

// ---------------- out = concat(fo, ro) @ out_W^T + out_b  (M=32768, N=512, K=1024) ---------
__global__ __launch_bounds__(256) void proj_out(
    const float* __restrict__ Xf, const float* __restrict__ Xr,
    const f16* __restrict__ Wo, const float* __restrict__ ob,
    float* __restrict__ out)
{
    const int blk = blockIdx.x;
    const int mb = (blk >> 3) << 6;
    const int nb = (blk & 7) << 6;
    const int w = threadIdx.x >> 6, ln15 = threadIdx.x & 15;
    const int kgrp = ((threadIdx.x & 63) >> 4) << 3;
    const int m = mb + w*16 + ln15;              // m = b*256 + t
    const int t = m & 255, b = m >> 8;
    const float* af_ = Xf + (((size_t)t*128 + b) << 9);
    const float* ar_ = Xr + (((size_t)(255 - t)*128 + b) << 9);
    f32x4 acc[4] = {{0,0,0,0},{0,0,0,0},{0,0,0,0},{0,0,0,0}};
    #pragma unroll 2
    for (int ks = 0; ks < 32; ++ks) {
        const int ko = (ks << 5) + kgrp;
        const f16x8 af = cvt8(ks < 16 ? af_ + ko : ar_ + (ko - 512));
        #pragma unroll
        for (int ctn = 0; ctn < 4; ++ctn) {
            const int n = nb + ctn*16 + ln15;
            const f16x8 bf = *(const f16x8*)(Wo + ((size_t)n << 10) + ko);
            acc[ctn] = __builtin_amdgcn_mfma_f32_16x16x32_f16(af, bf, acc[ctn], 0, 0, 0);
        }
    }
    const int r0 = mb + w*16 + (((threadIdx.x & 63) >> 4) << 2);
    #pragma unroll
    for (int ctn = 0; ctn < 4; ++ctn) {
        const int n = nb + ctn*16 + ln15;
        const float bb = ob[n];
        #pragma unroll
        for (int r = 0; r < 4; ++r)
            out[((size_t)(r0 + r) << 9) + n] = acc[ctn][r] + bb;
    }
}

// ---------------- hidden/cell projections (M=512, N=512, K=1024) ---------------------------
__global__ __launch_bounds__(256) void proj_state(
    const float* __restrict__ hT, const float* __restrict__ cT,
    const f16* __restrict__ Wh, const f16* __restrict__ Wc,
    const float* __restrict__ hb_, const float* __restrict__ cb_,
    float* __restrict__ out)
{
    const int blk = blockIdx.x;
    const int z = blk >> 6;
    const int sub = blk & 63;
    const int mb = (sub >> 3) << 6;
    const int nb = (sub & 7) << 6;
    const int w = threadIdx.x >> 6, ln15 = threadIdx.x & 15;
    const int kgrp = ((threadIdx.x & 63) >> 4) << 3;
    const int m = mb + w*16 + ln15;               // m = l*128 + b
    const int l = m >> 7, b = m & 127;
    const float* A = z ? cT : hT;
    const f16*  W  = z ? Wc : Wh;
    const float* bi = z ? cb_ : hb_;
    const float* a0 = A + (((size_t)(l*2 + 0)*128 + b) << 9);
    const float* a1 = A + (((size_t)(l*2 + 1)*128 + b) << 9);
    f32x4 acc[4] = {{0,0,0,0},{0,0,0,0},{0,0,0,0},{0,0,0,0}};
    for (int ks = 0; ks < 32; ++ks) {
        const int ko = (ks << 5) + kgrp;
        const f16x8 af = cvt8(ks < 16 ? a0 + ko : a1 + (ko - 512));
        #pragma unroll
        for (int ctn = 0; ctn < 4; ++ctn) {
            const int n = nb + ctn*16 + ln15;
            const f16x8 bf = *(const f16x8*)(W + ((size_t)n << 10) + ko);
            acc[ctn] = __builtin_amdgcn_mfma_f32_16x16x32_f16(af, bf, acc[ctn], 0, 0, 0);
        }
    }
    float* o = out + (size_t)z * 262144;
    const int r0 = mb + w*16 + (((threadIdx.x & 63) >> 4) << 2);
    #pragma unroll
    for (int ctn = 0; ctn < 4; ++ctn) {
        const int n = nb + ctn*16 + ln15;
        const float bb = bi[n];
        #pragma unroll
        for (int r = 0; r < 4; ++r)
            o[((size_t)(r0 + r) << 9) + n] = acc[ctn][r] + bb;
    }
}

extern "C" void kernel_launch(void* const* d_in, const int* in_sizes, int n_in,
                              void* d_out, int out_size, void* d_ws, size_t ws_size,
                              hipStream_t stream)
{
    const int*   enc  = (const int*)d_in[0];
    const float* emb  = (const float*)d_in[1];
    const float* Wih  = (const float*)d_in[2];
    const float* Whh  = (const float*)d_in[3];
    const float* bih  = (const float*)d_in[4];
    const float* bhh  = (const float*)d_in[5];
    const float* oW   = (const float*)d_in[6];
    const float* obv  = (const float*)d_in[7];
    const float* hW   = (const float*)d_in[8];
    const float* hbv  = (const float*)d_in[9];
    const float* cW   = (const float*)d_in[10];
    const float* cbv  = (const float*)d_in[11];
    float* out = (float*)d_out;
    char* ws = (char*)d_ws;

    float* Xf = (float*)(ws + OFF_XF);
    float* Xr = (float*)(ws + OFF_XR);
    f16* Wp   = (f16*)(ws + OFF_WP);
    f16* Wo   = (f16*)(ws + OFF_WO);
    f16* Wh   = (f16*)(ws + OFF_WH);
    f16* Wc   = (f16*)(ws + OFF_WC);
    float* bc = (float*)(ws + OFF_BC);
    f16* hb   = (f16*)(ws + OFF_HB);
    float* hT = (float*)(ws + OFF_HT);
    float* cT = (float*)(ws + OFF_CT);
    int* cnt  = (int*)(ws + OFF_CNT);

    (void)hipFuncSetAttribute((const void*)lstm_layer,
                              hipFuncAttributeMaxDynamicSharedMemorySize, 148480);

    prep_w<<<128, 256, 0, stream>>>(Wih, Whh, Wp);
    prep_misc<<<1538, 256, 0, stream>>>(bih, bhh, oW, hW, cW, Wo, Wh, Wc, bc, cnt);
    embed_relu<<<32768, 256, 0, stream>>>(enc, emb, Xf, Xr);
    for (int l = 0; l < 4; ++l)
        lstm_layer<<<128, 256, 148480, stream>>>(l, Wp, bc, Xf, Xr, hb, hT, cT, cnt);
    proj_out<<<4096, 256, 0, stream>>>(Xf, Xr, Wo, obv, out);
    proj_state<<<128, 256, 0, stream>>>(hT, cT, Wh, Wc, hbv, cbv, out + 16777216);
}

// Round 9
// 17147.160 us; speedup vs baseline: 1.1944x; 1.1944x over previous
//
#include <hip/hip_runtime.h>

typedef _Float16 f16;
typedef f16  f16x8 __attribute__((ext_vector_type(8)));
typedef __fp16 h16x2 __attribute__((ext_vector_type(2)));
typedef float f32x4 __attribute__((ext_vector_type(4)));
typedef float f32x16 __attribute__((ext_vector_type(16)));
typedef unsigned long long u64;

// problem dims: B=128, T=256, E=H=512, L=4, 4H=2048
// ws layout (bytes)
#define OFF_XF  0ull          // fwd activation stream (T,128,512) f32 : 64 MB
#define OFF_XR  67108864ull   // time-reversed stream                  : 64 MB
#define OFF_WP  134217728ull  // packed lstm weights f16, frag-ordered [L][32cb][128KB]: 16 MB
#define OFF_WO  150994944ull  // out_W  f16 [512][1024]
#define OFF_WH  152043520ull  // hid_W  f16
#define OFF_WC  153092096ull  // cell_W f16
#define OFF_BC  154140672ull  // combined bias f32 [L][2048] (packed order)
#define OFF_HB  154173440ull  // h exchange buf f16 [dir][parity][128][512]
#define OFF_HT  154697728ull  // hT f32 [L][dir][128][512]
#define OFF_CT  156794880ull  // cT f32
#define OFF_CNT 158892032ull  // progress slots int [16 grp][32 blk][16 pad]

__device__ __forceinline__ float sigm(float x) { return 1.0f / (1.0f + __expf(-x)); }
__device__ __forceinline__ float ftanh(float x) { return 1.0f - 2.0f / (__expf(2.0f * x) + 1.0f); }

__device__ __forceinline__ f16x8 cvt8(const float* p) {
    float4 a0 = *(const float4*)p;
    float4 a1 = *(const float4*)(p + 4);
    union { f16x8 v; h16x2 h[4]; } u;
    u.h[0] = __builtin_amdgcn_cvt_pkrtz(a0.x, a0.y);
    u.h[1] = __builtin_amdgcn_cvt_pkrtz(a0.z, a0.w);
    u.h[2] = __builtin_amdgcn_cvt_pkrtz(a1.x, a1.y);
    u.h[3] = __builtin_amdgcn_cvt_pkrtz(a1.z, a1.w);
    return u.v;
}

// ---------------- prep: LSTM weights -> fragment-ordered f16 tiles ------------------------
// Tile (l,cb): 64 packed cols (q = gate*16 + jl) x 1024 K, stored as
//   [ct(2)][frag(64)][lane(64)][8 f16]  so ds_read_b128 per lane is stride-1.
// frag f: k = (f>>5)*512 + (f&31)*16 + (lane>>5)*8 ; col q = ct*32 + (lane&31)
__global__ __launch_bounds__(256) void prep_w(
    const float* __restrict__ Wih, const float* __restrict__ Whh, f16* __restrict__ Wp)
{
    const int l = blockIdx.x >> 5, cb = blockIdx.x & 31;
    f16* dst = Wp + (size_t)blockIdx.x * 65536;
    for (int g = threadIdx.x; g < 8192; g += 256) {      // 8-elem groups
        const int ct = g >> 12;
        const int r  = g & 4095;
        const int f  = r >> 6;
        const int ln = r & 63;
        const int q  = ct*32 + (ln & 31);
        const int orig = (q >> 4)*512 + cb*16 + (q & 15);
        const int k0 = ((f >> 5) << 9) + (f & 31)*16 + ((ln >> 5) << 3);
        const float* src = (k0 < 512)
            ? Wih + (((size_t)(l*2048 + orig)) << 9) + k0
            : Whh + (((size_t)(l*2048 + orig)) << 9) + (k0 - 512);
        *(f16x8*)(dst + (size_t)g * 8) = cvt8(src);
    }
}

// ---------------- prep: proj weights f16, combined bias, progress slots -------------------
__global__ __launch_bounds__(256) void prep_misc(
    const float* __restrict__ bih, const float* __restrict__ bhh,
    const float* __restrict__ oW, const float* __restrict__ hW, const float* __restrict__ cW,
    f16* __restrict__ Wo, f16* __restrict__ Wh, f16* __restrict__ Wc,
    float* __restrict__ bc, int* __restrict__ prog)
{
    const int blk = blockIdx.x, tid = threadIdx.x;
    if (blk < 1536) {
        const int which = blk >> 9;
        const int n = blk & 511;
        const float* s = which == 0 ? oW : (which == 1 ? hW : cW);
        f16* d = which == 0 ? Wo : (which == 1 ? Wh : Wc);
        for (int k = tid; k < 1024; k += 256)
            d[((size_t)n << 10) + k] = (f16)s[((size_t)n << 10) + k];
    } else if (blk == 1536) {
        for (int i = tid; i < 8192; i += 256) {
            const int l = i >> 11, p = i & 2047;
            const int cb = p >> 6, gate = (p >> 4) & 3, j = p & 15;
            const int orig = l*2048 + gate*512 + cb*16 + j;
            bc[i] = bih[orig] + bhh[orig];
        }
    } else {
        for (int i = tid; i < 8192; i += 256) prog[i] = 0;   // 16*32*16
    }
}

// ---------------- embedding + relu, fwd and time-reversed streams -------------------------
__global__ __launch_bounds__(256) void embed_relu(
    const int* __restrict__ ids, const float* __restrict__ emb,
    float* __restrict__ Xf, float* __restrict__ Xr)
{
    const int blk = blockIdx.x;               // 0..32767
    const int b = blk >> 8, t = blk & 255;
    const int id = ids[b*256 + t];
    float2 v = *((const float2*)(emb + ((size_t)id << 9)) + threadIdx.x);
    v.x = fmaxf(v.x, 0.f); v.y = fmaxf(v.y, 0.f);
    const size_t e2 = (size_t)threadIdx.x * 2;
    *(float2*)(Xf + (((size_t)t*128 + b) << 9) + e2) = v;
    *(float2*)(Xr + (((size_t)(255 - t)*128 + b) << 9) + e2) = v;
}

// ---------------- persistent per-layer LSTM -----------------------------------------------
// grid 128; block b -> (dir,half) group g2=(b>>1)&3 on XCDs {2g2,2g2+1} (b%8 rr).
// Per step: X-half MFMAs first (no remote dep), then poll progress slots, residual write,
// batched IC h-loads (sched_barrier-fenced), h-half MFMAs, Gs bounce, elementwise, signal.
__global__ __launch_bounds__(256, 1) void lstm_layer(
    const int l,
    const f16* __restrict__ Wp, const float* __restrict__ bc,
    float* __restrict__ Xf, float* __restrict__ Xr,
    f16* __restrict__ hbuf, float* __restrict__ hT, float* __restrict__ cT,
    int* __restrict__ prog)
{
    extern __shared__ char smem[];
    f16*   Wlds = (f16*)smem;                 // 2ct x 64frag x 64lane x 8 f16 = 128KB
    float* Gs   = (float*)(smem + 131072);    // 64 x 65 f32

    const int tid = threadIdx.x;
    const int b   = blockIdx.x;
    const int g2  = (b >> 1) & 3;             // (dir,half) group
    const int cb  = ((b >> 3) << 1) | (b & 1);
    const int dir = g2 >> 1;
    const int half= g2 & 1;

    const int w   = tid >> 6;                 // wave id
    const int rt  = w >> 1, ct = w & 1;       // row-tile / col-tile quadrant
    const int ln  = tid & 63;
    const int l31 = ln & 31;
    const int hi  = ln >> 5;

    {   // stage pre-packed W tile (linear copy)
        const float4* src = (const float4*)(Wp + (size_t)(l*32 + cb) * 65536);
        float4* dst = (float4*)Wlds;
        for (int i = tid; i < 8192; i += 256) dst[i] = src[i];
    }

    float* X = dir ? Xr : Xf;
    f16* hb = hbuf + (size_t)dir * 131072;
    const int grp = (l*2 + dir)*2 + half;
    int* pg  = prog + grp*512;                // [32 blk][16 pad]
    int* pgs = pg + cb*16;                    // this block's slot

    const int arow = half*64 + rt*32 + l31;   // A row (batch index)
    const int kb0  = hi << 3;
    const f16* wbase = Wlds + (ct << 15);     // ct*32768 elements

    // elementwise mapping: thread -> row erow, 4 consecutive cols
    const int erow_r = tid >> 2;              // 0..63
    const int eb   = half*64 + erow_r;        // batch row
    const int cg4  = (tid & 3) << 2;          // local col base 0,4,8,12
    const int ecol = cb*16 + cg4;             // global hidden col
    const float4 bq_i = *(const float4*)(bc + l*2048 + cb*64 +      cg4);
    const float4 bq_f = *(const float4*)(bc + l*2048 + cb*64 + 16 + cg4);
    const float4 bq_g = *(const float4*)(bc + l*2048 + cb*64 + 32 + cg4);
    const float4 bq_o = *(const float4*)(bc + l*2048 + cb*64 + 48 + cg4);

    float creg[4] = {0.f, 0.f, 0.f, 0.f};
    float4 xd = {0.f, 0.f, 0.f, 0.f};

    __syncthreads();                          // W staged

    for (int t = 0; t < 256; ++t) {
        // ---- X-half first: depends only on X[t] (ready) + LDS weights ----
        f32x16 acc = {};
        const float* xrow = X + (((size_t)t) << 16) + (((size_t)arow) << 9);
        #pragma unroll
        for (int ks = 0; ks < 32; ++ks) {
            f16x8 af = cvt8(xrow + ks*16 + kb0);
            f16x8 bf = *(const f16x8*)(wbase + (ks << 9) + (ln << 3));
            acc = __builtin_amdgcn_mfma_f32_32x32x16_f16(af, bf, acc, 0, 0, 0);
        }

        if (t > 0) {
            // ---- poll (wave 0 only): all 32 blocks of group reached step t ----
            if (tid < 64) {
                int gd = 0;
                for (;;) {
                    int v = 0x7fffffff;
                    if (tid < 32)
                        v = __hip_atomic_load(pg + tid*16, __ATOMIC_RELAXED, __HIP_MEMORY_SCOPE_AGENT);
                    if (__all(v >= t)) break;
                    __builtin_amdgcn_s_sleep(2);
                    if (++gd > (1 << 18)) break;     // deadlock bail
                }
            }
            __syncthreads();
            __builtin_amdgcn_sched_barrier(0);
            // deferred residual write of X[t-1] (all group reads of it are done)
            *(float4*)(X + (((size_t)(t - 1)) << 16) + (((size_t)eb) << 9) + ecol) = xd;

            // ---- batched h loads (IC, relaxed) — fenced so they pipeline ----
            f16x8 uu[32];
            {
                const f16* hrow = hb + (((size_t)((t - 1) & 1)) << 16) + (((size_t)arow) << 9);
                #pragma unroll
                for (int ks = 0; ks < 32; ++ks) {
                    const u64* hp = (const u64*)(hrow + ks*16 + kb0);
                    union { u64 q[2]; f16x8 v; } uv;
                    uv.q[0] = __hip_atomic_load(hp,     __ATOMIC_RELAXED, __HIP_MEMORY_SCOPE_AGENT);
                    uv.q[1] = __hip_atomic_load(hp + 1, __ATOMIC_RELAXED, __HIP_MEMORY_SCOPE_AGENT);
                    uu[ks] = uv.v;
                }
            }
            __builtin_amdgcn_sched_barrier(0);
            // ---- h-half MFMAs ----
            #pragma unroll
            for (int ks = 0; ks < 32; ++ks) {
                f16x8 bf = *(const f16x8*)(wbase + ((32 + ks) << 9) + (ln << 3));
                acc = __builtin_amdgcn_mfma_f32_32x32x16_f16(uu[ks], bf, acc, 0, 0, 0);
            }
        }

        // ---- gates -> LDS bounce (65-pad) ----
        {
            const int grow0 = rt*32 + 4*hi;
            const int q = ct*32 + l31;
            #pragma unroll
            for (int r = 0; r < 16; ++r)
                Gs[(grow0 + (r & 3) + 8*(r >> 2))*65 + q] = acc[r];
        }
        __syncthreads();

        // ---- elementwise: row erow_r, cols cg4..cg4+3 ----
        {
            const float* gr = Gs + erow_r*65;
            float hq[4];
            #pragma unroll
            for (int j = 0; j < 4; ++j) {
                const float gi = gr[     cg4 + j] + ((const float*)&bq_i)[j];
                const float gf = gr[16 + cg4 + j] + ((const float*)&bq_f)[j];
                const float gg = gr[32 + cg4 + j] + ((const float*)&bq_g)[j];
                const float go = gr[48 + cg4 + j] + ((const float*)&bq_o)[j];
                const float cn = sigm(gf)*creg[j] + sigm(gi)*ftanh(gg);
                const float hv = sigm(go)*ftanh(cn);
                creg[j] = cn;
                hq[j] = hv;
            }
            const float4 xold = *(const float4*)(X + (((size_t)t) << 16) + (((size_t)eb) << 9) + ecol);
            xd.x = xold.x + hq[0]; xd.y = xold.y + hq[1];
            xd.z = xold.z + hq[2]; xd.w = xold.w + hq[3];

            union { u64 q; f16 h4[4]; } hu;
            hu.h4[0]=(f16)hq[0]; hu.h4[1]=(f16)hq[1]; hu.h4[2]=(f16)hq[2]; hu.h4[3]=(f16)hq[3];
            __hip_atomic_store((u64*)(hb + (((size_t)(t & 1)) << 16) + (((size_t)eb) << 9) + ecol), hu.q,
                               __ATOMIC_RELAXED, __HIP_MEMORY_SCOPE_AGENT);
            if (t == 255) {
                const size_t o = (((size_t)(l*2 + dir)*128 + eb) << 9) + ecol;
                *(float4*)(hT + o) = make_float4(hq[0], hq[1], hq[2], hq[3]);
                *(float4*)(cT + o) = make_float4(creg[0], creg[1], creg[2], creg[3]);
            }
        }
        __syncthreads();   // drains vmcnt: this block's h stores are at IC
        if (tid == 0)
            __hip_atomic_store(pgs, t + 1, __ATOMIC_RELAXED, __HIP_MEMORY_SCOPE_AGENT);
    }

    // flush final deferred residual write (after everyone has read X[255])
    if (tid < 64) {
        int gd = 0;
        for (;;) {
            int v = 0x7fffffff;
            if (tid < 32)
                v = __hip_atomic_load(pg + tid*16, __ATOMIC_RELAXED, __HIP_MEMORY_SCOPE_AGENT);
            if (__all(v >= 256)) break;
            __builtin_amdgcn_s_sleep(2);
            if (++gd > (1 << 18)) break;
        }
    }
    __syncthreads();
    *(float4*)(X + (((size_t)255) << 16) + (((size_t)eb) << 9) + ecol) = xd;
}

// ---------------- out = concat(fo, ro) @ out_W^T + out_b  (M=32768, N=512, K=1024) ---------
__global__ __launch_bounds__(256) void proj_out(
    const float* __restrict__ Xf, const float* __restrict__ Xr,
    const f16* __restrict__ Wo, const float* __restrict__ ob,
    float* __restrict__ out)
{
    const int blk = blockIdx.x;
    const int mb = (blk >> 3) << 6;
    const int nb = (blk & 7) << 6;
    const int w = threadIdx.x >> 6, ln15 = threadIdx.x & 15;
    const int kgrp = ((threadIdx.x & 63) >> 4) << 3;
    const int m = mb + w*16 + ln15;              // m = b*256 + t
    const int t = m & 255, b = m >> 8;
    const float* af_ = Xf + (((size_t)t*128 + b) << 9);
    const float* ar_ = Xr + (((size_t)(255 - t)*128 + b) << 9);
    f32x4 acc[4] = {{0,0,0,0},{0,0,0,0},{0,0,0,0},{0,0,0,0}};
    #pragma unroll 2
    for (int ks = 0; ks < 32; ++ks) {
        const int ko = (ks << 5) + kgrp;
        const f16x8 af = cvt8(ks < 16 ? af_ + ko : ar_ + (ko - 512));
        #pragma unroll
        for (int ctn = 0; ctn < 4; ++ctn) {
            const int n = nb + ctn*16 + ln15;
            const f16x8 bf = *(const f16x8*)(Wo + ((size_t)n << 10) + ko);
            acc[ctn] = __builtin_amdgcn_mfma_f32_16x16x32_f16(af, bf, acc[ctn], 0, 0, 0);
        }
    }
    const int r0 = mb + w*16 + (((threadIdx.x & 63) >> 4) << 2);
    #pragma unroll
    for (int ctn = 0; ctn < 4; ++ctn) {
        const int n = nb + ctn*16 + ln15;
        const float bb = ob[n];
        #pragma unroll
        for (int r = 0; r < 4; ++r)
            out[((size_t)(r0 + r) << 9) + n] = acc[ctn][r] + bb;
    }
}

// ---------------- hidden/cell projections (M=512, N=512, K=1024) ---------------------------
__global__ __launch_bounds__(256) void proj_state(
    const float* __restrict__ hT, const float* __restrict__ cT,
    const f16* __restrict__ Wh, const f16* __restrict__ Wc,
    const float* __restrict__ hb_, const float* __restrict__ cb_,
    float* __restrict__ out)
{
    const int blk = blockIdx.x;
    const int z = blk >> 6;
    const int sub = blk & 63;
    const int mb = (sub >> 3) << 6;
    const int nb = (sub & 7) << 6;
    const int w = threadIdx.x >> 6, ln15 = threadIdx.x & 15;
    const int kgrp = ((threadIdx.x & 63) >> 4) << 3;
    const int m = mb + w*16 + ln15;               // m = l*128 + b
    const int l = m >> 7, b = m & 127;
    const float* A = z ? cT : hT;
    const f16*  W  = z ? Wc : Wh;
    const float* bi = z ? cb_ : hb_;
    const float* a0 = A + (((size_t)(l*2 + 0)*128 + b) << 9);
    const float* a1 = A + (((size_t)(l*2 + 1)*128 + b) << 9);
    f32x4 acc[4] = {{0,0,0,0},{0,0,0,0},{0,0,0,0},{0,0,0,0}};
    for (int ks = 0; ks < 32; ++ks) {
        const int ko = (ks << 5) + kgrp;
        const f16x8 af = cvt8(ks < 16 ? a0 + ko : a1 + (ko - 512));
        #pragma unroll
        for (int ctn = 0; ctn < 4; ++ctn) {
            const int n = nb + ctn*16 + ln15;
            const f16x8 bf = *(const f16x8*)(W + ((size_t)n << 10) + ko);
            acc[ctn] = __builtin_amdgcn_mfma_f32_16x16x32_f16(af, bf, acc[ctn], 0, 0, 0);
        }
    }
    float* o = out + (size_t)z * 262144;
    const int r0 = mb + w*16 + (((threadIdx.x & 63) >> 4) << 2);
    #pragma unroll
    for (int ctn = 0; ctn < 4; ++ctn) {
        const int n = nb + ctn*16 + ln15;
        const float bb = bi[n];
        #pragma unroll
        for (int r = 0; r < 4; ++r)
            o[((size_t)(r0 + r) << 9) + n] = acc[ctn][r] + bb;
    }
}

extern "C" void kernel_launch(void* const* d_in, const int* in_sizes, int n_in,
                              void* d_out, int out_size, void* d_ws, size_t ws_size,
                              hipStream_t stream)
{
    const int*   enc  = (const int*)d_in[0];
    const float* emb  = (const float*)d_in[1];
    const float* Wih  = (const float*)d_in[2];
    const float* Whh  = (const float*)d_in[3];
    const float* bih  = (const float*)d_in[4];
    const float* bhh  = (const float*)d_in[5];
    const float* oW   = (const float*)d_in[6];
    const float* obv  = (const float*)d_in[7];
    const float* hW   = (const float*)d_in[8];
    const float* hbv  = (const float*)d_in[9];
    const float* cW   = (const float*)d_in[10];
    const float* cbv  = (const float*)d_in[11];
    float* out = (float*)d_out;
    char* ws = (char*)d_ws;

    float* Xf = (float*)(ws + OFF_XF);
    float* Xr = (float*)(ws + OFF_XR);
    f16* Wp   = (f16*)(ws + OFF_WP);
    f16* Wo   = (f16*)(ws + OFF_WO);
    f16* Wh   = (f16*)(ws + OFF_WH);
    f16* Wc   = (f16*)(ws + OFF_WC);
    float* bc = (float*)(ws + OFF_BC);
    f16* hb   = (f16*)(ws + OFF_HB);
    float* hT = (float*)(ws + OFF_HT);
    float* cT = (float*)(ws + OFF_CT);
    int* prog = (int*)(ws + OFF_CNT);

    (void)hipFuncSetAttribute((const void*)lstm_layer,
                              hipFuncAttributeMaxDynamicSharedMemorySize, 147712);

    prep_w<<<128, 256, 0, stream>>>(Wih, Whh, Wp);
    prep_misc<<<1538, 256, 0, stream>>>(bih, bhh, oW, hW, cW, Wo, Wh, Wc, bc, prog);
    embed_relu<<<32768, 256, 0, stream>>>(enc, emb, Xf, Xr);
    for (int l = 0; l < 4; ++l)
        lstm_layer<<<128, 256, 147712, stream>>>(l, Wp, bc, Xf, Xr, hb, hT, cT, prog);
    proj_out<<<4096, 256, 0, stream>>>(Xf, Xr, Wo, obv, out);
    proj_state<<<128, 256, 0, stream>>>(hT, cT, Wh, Wc, hbv, cbv, out + 16777216);
}